// Round 1
// baseline (8509.443 us; speedup 1.0000x reference)
//
#include <hip/hip_runtime.h>

#define NQ 8
#define KCODES 4096
#define DIMS 128
#define BATCH 8
#define SEQ 4096
#define ROWS (BATCH*SEQ)            // 32768
#define TM 32                       // rows per block
#define RESPAD 36                   // padded LDS row length
#define OUT_ELEMS (BATCH*DIMS*SEQ)  // 4194304
#define IDX_ELEMS (BATCH*SEQ*NQ)    // 262144
#define LOSS_DIV (1.0f/33554432.0f) // 1/(Q*B*N*D)

// ---------------- prep: transpose codebooks cb[q][k][d] -> cbT[q][d][k] -------------
__global__ void prep_transpose(const float* __restrict__ cb, float* __restrict__ cbT,
                               float* __restrict__ loss_accum) {
    __shared__ float tile[32][33];
    int bx = blockIdx.x;
    if (bx == 0 && threadIdx.x == 0) loss_accum[0] = 0.f;
    int qi  = bx >> 9;          // 512 tiles per q (128 k-tiles * 4 d-tiles)
    int rem = bx & 511;
    int kt  = rem >> 2;         // 0..127
    int dt  = rem & 3;          // 0..3
    int k0 = kt * 32, d0 = dt * 32;
    int tx = threadIdx.x & 31, ty = threadIdx.x >> 5;   // 32 x 8
    const float* src = cb  + (size_t)qi * KCODES * DIMS;
    float*       dst = cbT + (size_t)qi * DIMS * KCODES;
#pragma unroll
    for (int r = 0; r < 4; ++r) {
        int k = k0 + ty + r * 8;
        tile[ty + r * 8][tx] = src[(size_t)k * DIMS + d0 + tx];
    }
    __syncthreads();
#pragma unroll
    for (int r = 0; r < 4; ++r) {
        int d = d0 + ty + r * 8;
        dst[(size_t)d * KCODES + k0 + tx] = tile[tx][ty + r * 8];
    }
}

// ---------------- prep: c_sq[q][k] = sum_d cb^2 -------------
__global__ void prep_csq(const float* __restrict__ cb, float* __restrict__ csq) {
    int c = blockIdx.x * 256 + threadIdx.x;   // 0..32767 = q*4096+k
    const float4* p = (const float4*)(cb + (size_t)c * DIMS);
    float s = 0.f;
#pragma unroll
    for (int i = 0; i < 32; ++i) {
        float4 v = p[i];
        s += v.x * v.x + v.y * v.y + v.z * v.z + v.w * v.w;
    }
    csq[c] = s;
}

// ---------------- main RVQ kernel -------------
__launch_bounds__(256, 3)
__global__ void rvq_main(const float* __restrict__ x, const float* __restrict__ cb,
                         const float* __restrict__ cbT, const float* __restrict__ csq,
                         float* __restrict__ out, float* __restrict__ loss_accum) {
    __shared__ float res[DIMS][RESPAD];   // transposed residual res[d][row]
    __shared__ float bbd[TM][33];
    __shared__ int   bbi[TM][33];
    __shared__ int   bfin[TM];
    __shared__ float rsqbuf[TM];

    int tid = threadIdx.x;
    int r0  = blockIdx.x * TM;
    int b   = r0 >> 12;            // / SEQ
    int n0  = r0 & (SEQ - 1);
    const float* xb = x + (size_t)b * DIMS * SEQ + n0;

    // load x rows (strided gather, coalesced over n) into transposed LDS residual
    {
        int d = tid >> 1, i0 = (tid & 1) * 16;
        const float* src = xb + (size_t)d * SEQ + i0;
#pragma unroll
        for (int t = 0; t < 4; ++t) {
            float4 v = *(const float4*)(src + 4 * t);
            *(float4*)&res[d][i0 + 4 * t] = v;
        }
    }

    float lossacc = 0.f;
    int col = tid & 31;   // code column 0..31
    int rg  = tid >> 5;   // row group 0..7 (4 rows each)

    for (int q = 0; q < NQ; ++q) {
        __syncthreads();   // residual (or init load) complete
        // per-row ||r||^2 (serial d, same scale as numpy; only affects rounding grid)
        if (tid < TM) {
            float s = 0.f;
#pragma unroll
            for (int d = 0; d < DIMS; ++d) { float v = res[d][tid]; s = fmaf(v, v, s); }
            rsqbuf[tid] = s;
        }
        __syncthreads();

        const float* cbTq = cbT + (size_t)q * DIMS * KCODES;
        const float* csqq = csq + q * KCODES;
        float rsq[4];
#pragma unroll
        for (int r = 0; r < 4; ++r) rsq[r] = rsqbuf[rg * 4 + r];

        float bestd[4];
        int   besti[4];
#pragma unroll
        for (int r = 0; r < 4; ++r) { bestd[r] = 3.4e38f; besti[r] = 0; }

        for (int it = 0; it < 8; ++it) {
            int kb = it * 512 + col * 16;
            float acc[4][16];
#pragma unroll
            for (int r = 0; r < 4; ++r)
#pragma unroll
                for (int j = 0; j < 16; ++j) acc[r][j] = 0.f;

            for (int d = 0; d < DIMS; ++d) {
                float4 r4 = *(const float4*)&res[d][rg * 4];
                float rr[4] = { r4.x, r4.y, r4.z, r4.w };
                const float4* cp = (const float4*)(cbTq + ((size_t)d << 12) + kb);
#pragma unroll
                for (int jj = 0; jj < 4; ++jj) {
                    float4 c = cp[jj];
                    float cc[4] = { c.x, c.y, c.z, c.w };
#pragma unroll
                    for (int r = 0; r < 4; ++r)
#pragma unroll
                        for (int cj = 0; cj < 4; ++cj)
                            acc[r][jj * 4 + cj] = fmaf(rr[r], cc[cj], acc[r][jj * 4 + cj]);
                }
            }
            // dist = (rsq - 2*dot) + csq  (same op order as reference)
#pragma unroll
            for (int j = 0; j < 16; ++j) {
                float cs = csqq[kb + j];
#pragma unroll
                for (int r = 0; r < 4; ++r) {
                    float dist = (rsq[r] - 2.f * acc[r][j]) + cs;
                    int   k    = kb + j;
                    if (dist < bestd[r]) { bestd[r] = dist; besti[r] = k; }
                }
            }
        }
        // candidates -> LDS
#pragma unroll
        for (int r = 0; r < 4; ++r) {
            bbd[rg * 4 + r][col] = bestd[r];
            bbi[rg * 4 + r][col] = besti[r];
        }
        __syncthreads();
        // reduce across 32 columns per row, numpy first-index tie-break
        if (tid < TM) {
            float bd = bbd[tid][0]; int bi = bbi[tid][0];
            for (int c2 = 1; c2 < 32; ++c2) {
                float dd = bbd[tid][c2]; int ii = bbi[tid][c2];
                if (dd < bd || (dd == bd && ii < bi)) { bd = dd; bi = ii; }
            }
            bfin[tid] = bi;
            out[OUT_ELEMS + (size_t)(r0 + tid) * NQ + q] = (float)bi;  // indices as f32
        }
        __syncthreads();
        // residual update + loss accumulation
        {
            int row = tid >> 3, d0 = (tid & 7) * 16;
            int bi = bfin[row];
            const float* cv = cb + ((size_t)q * KCODES + bi) * DIMS + d0;
#pragma unroll
            for (int t = 0; t < 16; ++t) {
                float nv = res[d0 + t][row] - cv[t];
                res[d0 + t][row] = nv;
                lossacc = fmaf(nv, nv, lossacc);
            }
        }
    }

    // loss reduction (reuse bbd as flat scratch)
    __syncthreads();
    float* red = (float*)bbd;
    red[tid] = lossacc;
    __syncthreads();
    for (int s = 128; s > 0; s >>= 1) {
        if (tid < s) red[tid] += red[tid + s];
        __syncthreads();
    }
    if (tid == 0) atomicAdd(loss_accum, red[0]);

    // quantized output: out = x - final_residual
    {
        int d = tid >> 1, i0 = (tid & 1) * 16;
        const float* src = xb + (size_t)d * SEQ + i0;
        float* dst = out + (size_t)b * DIMS * SEQ + (size_t)d * SEQ + n0 + i0;
#pragma unroll
        for (int t = 0; t < 4; ++t) {
            float4 v  = *(const float4*)(src + 4 * t);
            float4 rr = *(const float4*)&res[d][i0 + 4 * t];
            v.x -= rr.x; v.y -= rr.y; v.z -= rr.z; v.w -= rr.w;
            *(float4*)(dst + 4 * t) = v;
        }
    }
}

__global__ void finish_loss(const float* __restrict__ loss_accum, float* __restrict__ out) {
    out[OUT_ELEMS + IDX_ELEMS] = loss_accum[0] * LOSS_DIV;
}

extern "C" void kernel_launch(void* const* d_in, const int* in_sizes, int n_in,
                              void* d_out, int out_size, void* d_ws, size_t ws_size,
                              hipStream_t stream) {
    const float* x  = (const float*)d_in[0];
    const float* cb = (const float*)d_in[1];
    float* out = (float*)d_out;
    char*  ws  = (char*)d_ws;

    float* loss_accum = (float*)ws;
    float* cbT = (float*)(ws + 256);
    float* csq = (float*)(ws + 256 + (size_t)NQ * DIMS * KCODES * sizeof(float));
    // ws needed: 256 + 16 MiB + 128 KiB  (assumed <= ws_size)

    hipLaunchKernelGGL(prep_transpose, dim3(NQ * 128 * 4), dim3(256), 0, stream, cb, cbT, loss_accum);
    hipLaunchKernelGGL(prep_csq, dim3(128), dim3(256), 0, stream, cb, csq);
    hipLaunchKernelGGL(rvq_main, dim3(ROWS / TM), dim3(256), 0, stream,
                       x, cb, cbT, csq, out, loss_accum);
    hipLaunchKernelGGL(finish_loss, dim3(1), dim3(1), 0, stream, loss_accum, out);
}

// Round 2
// 1309.155 us; speedup vs baseline: 6.4999x; 6.4999x over previous
//
#include <hip/hip_runtime.h>

typedef _Float16 half8 __attribute__((ext_vector_type(8)));
typedef float    float4v __attribute__((ext_vector_type(4)));

#define NQ 8
#define KCODES 4096
#define DIMS 128
#define BATCH 8
#define SEQ 4096
#define ROWS (BATCH*SEQ)            // 32768
#define TM 64                       // rows per block
#define NBLK (ROWS/TM)              // 512
#define RESPAD 132                  // res row stride (floats), 16B-aligned
#define OUT_ELEMS (BATCH*DIMS*SEQ)  // 4194304
#define IDX_ELEMS (BATCH*SEQ*NQ)    // 262144
#define LOSS_DIV (1.0f/33554432.0f) // 1/(Q*B*N*D)
#define FRAG_HALVES ((size_t)NQ*4*256*64*8)   // 4.19M f16 = 8 MB per hi/lo

// ---------------- prep: c_sq[q][k] = sum_d cb^2 (identical numerics to round 1) ----
__global__ void prep_csq(const float* __restrict__ cb, float* __restrict__ csq) {
    int c = blockIdx.x * 256 + threadIdx.x;   // q*4096+k
    const float4* p = (const float4*)(cb + (size_t)c * DIMS);
    float s = 0.f;
#pragma unroll
    for (int i = 0; i < 32; ++i) {
        float4 v = p[i];
        s += v.x * v.x + v.y * v.y + v.z * v.z + v.w * v.w;
    }
    csq[c] = s;
}

// ---------------- prep: codebook -> f16 hi/lo MFMA B-fragments ----------------------
// Fragment layout for mfma_f32_16x16x32_f16 B-operand:
//   lane l holds B[k=(l>>4)*8+j][n=l&15], j=0..7 (8 f16 = 16B = one dwordx4).
// Storage: frag g = ((q*4+kb)*256+nt)*64+lane at bhi/blo + g*8 halves.
__global__ void prep_frags(const float* __restrict__ cb, _Float16* __restrict__ bhi,
                           _Float16* __restrict__ blo, float* __restrict__ loss_accum) {
    int g = blockIdx.x * 256 + threadIdx.x;   // 524288 total
    if (g == 0) loss_accum[0] = 0.f;
    int lane = g & 63;
    int nt   = (g >> 6) & 255;
    int kb   = (g >> 14) & 3;
    int q    = g >> 16;
    int code = nt * 16 + (lane & 15);
    int k0   = kb * 32 + ((lane >> 4) * 8);
    const float* src = cb + ((size_t)q * KCODES + code) * DIMS + k0;
    float4 v0 = *(const float4*)(src);
    float4 v1 = *(const float4*)(src + 4);
    float f[8] = { v0.x, v0.y, v0.z, v0.w, v1.x, v1.y, v1.z, v1.w };
    half8 h, l;
#pragma unroll
    for (int j = 0; j < 8; ++j) {
        _Float16 hh = (_Float16)f[j];
        h[j] = hh;
        l[j] = (_Float16)(f[j] - (float)hh);
    }
    *(half8*)(bhi + (size_t)g * 8) = h;
    *(half8*)(blo + (size_t)g * 8) = l;
}

// ---------------- main RVQ kernel ---------------------------------------------------
__launch_bounds__(256, 2)
__global__ void rvq_main(const float* __restrict__ x, const float* __restrict__ cb,
                         const _Float16* __restrict__ bhi, const _Float16* __restrict__ blo,
                         const float* __restrict__ csq,
                         float* __restrict__ out, float* __restrict__ loss_accum) {
    __shared__ float res[TM][RESPAD];   // residual, row-major fp32
    __shared__ float wbd[4][TM];        // per-wave best dist
    __shared__ float wbi[4][TM];        // per-wave best idx (as float)
    __shared__ float fbin[TM];          // final best idx per row
    __shared__ float red[256];

    int tid  = threadIdx.x;
    int lane = tid & 63;
    int wv   = tid >> 6;
    int r0   = blockIdx.x * TM;
    int b    = r0 >> 12;                // / SEQ
    int n0   = r0 & (SEQ - 1);
    const float* xb = x + (size_t)b * DIMS * SEQ + n0;

    // load x[b][d][n0..n0+63] into res[n][d] (coalesced along n, scatter into LDS)
    {
        int d = tid >> 1, half = (tid & 1) * 32;
        const float* src = xb + (size_t)d * SEQ + half;
#pragma unroll
        for (int t4 = 0; t4 < 8; ++t4) {
            float4 v = *(const float4*)(src + t4 * 4);
            res[half + t4 * 4 + 0][d] = v.x;
            res[half + t4 * 4 + 1][d] = v.y;
            res[half + t4 * 4 + 2][d] = v.z;
            res[half + t4 * 4 + 3][d] = v.w;
        }
    }

    float lossacc = 0.f;

    for (int q = 0; q < NQ; ++q) {
        __syncthreads();   // res stable

        // build A fragments (hi/lo) in registers: A[m=lane&15][k=(lane>>4)*8+j]
        half8 ahi[4][4], alo[4][4];
#pragma unroll
        for (int mt = 0; mt < 4; ++mt)
#pragma unroll
        for (int kb = 0; kb < 4; ++kb) {
            int row = mt * 16 + (lane & 15);
            int k0  = kb * 32 + (lane >> 4) * 8;
            float4 v0 = *(const float4*)&res[row][k0];
            float4 v1 = *(const float4*)&res[row][k0 + 4];
            float f[8] = { v0.x, v0.y, v0.z, v0.w, v1.x, v1.y, v1.z, v1.w };
            half8 h, l;
#pragma unroll
            for (int j = 0; j < 8; ++j) {
                _Float16 hh = (_Float16)f[j];
                h[j] = hh;
                l[j] = (_Float16)(f[j] - (float)hh);
            }
            ahi[mt][kb] = h;
            alo[mt][kb] = l;
        }

        const _Float16* bq_hi = bhi + (size_t)q * (4 * 256 * 64 * 8);
        const _Float16* bq_lo = blo + (size_t)q * (4 * 256 * 64 * 8);
        const float*    csqq  = csq + q * KCODES;

        float bestd[4][4], besti[4][4];
#pragma unroll
        for (int mt = 0; mt < 4; ++mt)
#pragma unroll
        for (int r = 0; r < 4; ++r) { bestd[mt][r] = 3.4e38f; besti[mt][r] = 0.f; }

        // each wave owns n-tiles [wv*64, wv*64+64)
        int ntEnd = wv * 64 + 64;
        for (int nt = wv * 64; nt < ntEnd; ++nt) {
            half8 bh[4], bl[4];
#pragma unroll
            for (int kb = 0; kb < 4; ++kb) {
                size_t off = (((size_t)kb * 256 + nt) * 64 + lane) * 8;
                bh[kb] = *(const half8*)(bq_hi + off);
                bl[kb] = *(const half8*)(bq_lo + off);
            }
            float cs = csqq[nt * 16 + (lane & 15)];

            float4v acc[4];
            float4v z = { 0.f, 0.f, 0.f, 0.f };
#pragma unroll
            for (int mt = 0; mt < 4; ++mt) acc[mt] = z;

#pragma unroll
            for (int kb = 0; kb < 4; ++kb) {
#pragma unroll
                for (int mt = 0; mt < 4; ++mt) {
                    acc[mt] = __builtin_amdgcn_mfma_f32_16x16x32_f16(ahi[mt][kb], bh[kb], acc[mt], 0, 0, 0);
                    acc[mt] = __builtin_amdgcn_mfma_f32_16x16x32_f16(ahi[mt][kb], bl[kb], acc[mt], 0, 0, 0);
                    acc[mt] = __builtin_amdgcn_mfma_f32_16x16x32_f16(alo[mt][kb], bh[kb], acc[mt], 0, 0, 0);
                }
            }

            // ranking key: csq - 2*dot (rsq is per-row constant -> argmin-invariant)
            float fidx = (float)(nt * 16 + (lane & 15));
#pragma unroll
            for (int mt = 0; mt < 4; ++mt)
#pragma unroll
            for (int r = 0; r < 4; ++r) {
                float key = fmaf(acc[mt][r], -2.0f, cs);
                if (key < bestd[mt][r]) { bestd[mt][r] = key; besti[mt][r] = fidx; }
            }
        }

        // reduce across the 16 lanes sharing each row (low 4 lane bits)
#pragma unroll
        for (int mask = 1; mask <= 8; mask <<= 1) {
#pragma unroll
            for (int mt = 0; mt < 4; ++mt)
#pragma unroll
            for (int r = 0; r < 4; ++r) {
                float od = __shfl_xor(bestd[mt][r], mask, 64);
                float oi = __shfl_xor(besti[mt][r], mask, 64);
                if (od < bestd[mt][r] || (od == bestd[mt][r] && oi < besti[mt][r])) {
                    bestd[mt][r] = od;
                    besti[mt][r] = oi;
                }
            }
        }
        if ((lane & 15) == 0) {
            int qd = lane >> 4;
#pragma unroll
            for (int mt = 0; mt < 4; ++mt)
#pragma unroll
            for (int r = 0; r < 4; ++r) {
                int row = mt * 16 + qd * 4 + r;
                wbd[wv][row] = bestd[mt][r];
                wbi[wv][row] = besti[mt][r];
            }
        }
        __syncthreads();

        // cross-wave reduce (waves cover ascending code ranges; tie -> smaller idx)
        if (tid < TM) {
            float bd = wbd[0][tid], bi = wbi[0][tid];
#pragma unroll
            for (int w = 1; w < 4; ++w) {
                float dd = wbd[w][tid], ii = wbi[w][tid];
                if (dd < bd || (dd == bd && ii < bi)) { bd = dd; bi = ii; }
            }
            fbin[tid] = bi;
            out[OUT_ELEMS + (size_t)(r0 + tid) * NQ + q] = bi;   // index output (float)
        }
        __syncthreads();

        // residual update + commitment-loss accumulation
        {
            int row = tid >> 2, d0 = (tid & 3) * 32;
            int bi = (int)fbin[row];
            const float* cv = cb + ((size_t)q * KCODES + bi) * DIMS + d0;
#pragma unroll
            for (int t4 = 0; t4 < 8; ++t4) {
                float4 c4 = *(const float4*)(cv + t4 * 4);
                float* rp = &res[row][d0 + t4 * 4];
                float v0 = rp[0] - c4.x; rp[0] = v0; lossacc = fmaf(v0, v0, lossacc);
                float v1 = rp[1] - c4.y; rp[1] = v1; lossacc = fmaf(v1, v1, lossacc);
                float v2 = rp[2] - c4.z; rp[2] = v2; lossacc = fmaf(v2, v2, lossacc);
                float v3 = rp[3] - c4.w; rp[3] = v3; lossacc = fmaf(v3, v3, lossacc);
            }
        }
    }

    // loss reduction
    __syncthreads();
    red[tid] = lossacc;
    __syncthreads();
    for (int s = 128; s > 0; s >>= 1) {
        if (tid < s) red[tid] += red[tid + s];
        __syncthreads();
    }
    if (tid == 0) atomicAdd(loss_accum, red[0]);

    // quantized output: out = x - final_residual
    {
        int d = tid >> 1, half = (tid & 1) * 32;
        const float* src = xb + (size_t)d * SEQ + half;
        float* dst = out + (size_t)b * DIMS * SEQ + (size_t)d * SEQ + n0 + half;
#pragma unroll
        for (int t4 = 0; t4 < 8; ++t4) {
            float4 v = *(const float4*)(src + t4 * 4);
            v.x -= res[half + t4 * 4 + 0][d];
            v.y -= res[half + t4 * 4 + 1][d];
            v.z -= res[half + t4 * 4 + 2][d];
            v.w -= res[half + t4 * 4 + 3][d];
            *(float4*)(dst + t4 * 4) = v;
        }
    }
}

__global__ void finish_loss(const float* __restrict__ loss_accum, float* __restrict__ out) {
    out[OUT_ELEMS + IDX_ELEMS] = loss_accum[0] * LOSS_DIV;
}

extern "C" void kernel_launch(void* const* d_in, const int* in_sizes, int n_in,
                              void* d_out, int out_size, void* d_ws, size_t ws_size,
                              hipStream_t stream) {
    const float* x  = (const float*)d_in[0];
    const float* cb = (const float*)d_in[1];
    float* out = (float*)d_out;
    char*  ws  = (char*)d_ws;

    float*     loss_accum = (float*)ws;
    float*     csq = (float*)(ws + 256);
    _Float16*  bhi = (_Float16*)(ws + 256 + 131072);
    _Float16*  blo = (_Float16*)(ws + 256 + 131072 + FRAG_HALVES * 2);
    // ws needed: 256 + 128KiB + 16MiB (same footprint class as round 1)

    hipLaunchKernelGGL(prep_csq,   dim3(128),  dim3(256), 0, stream, cb, csq);
    hipLaunchKernelGGL(prep_frags, dim3(2048), dim3(256), 0, stream, cb, bhi, blo, loss_accum);
    hipLaunchKernelGGL(rvq_main,   dim3(NBLK), dim3(256), 0, stream,
                       x, cb, bhi, blo, csq, out, loss_accum);
    hipLaunchKernelGGL(finish_loss, dim3(1), dim3(1), 0, stream, loss_accum, out);
}

// Round 3
// 861.033 us; speedup vs baseline: 9.8828x; 1.5204x over previous
//
#include <hip/hip_runtime.h>

typedef _Float16 half8 __attribute__((ext_vector_type(8)));
typedef float    float4v __attribute__((ext_vector_type(4)));

#define NQ 8
#define KCODES 4096
#define DIMS 128
#define BATCH 8
#define SEQ 4096
#define ROWS (BATCH*SEQ)            // 32768
#define TM 64                       // rows per block
#define NBLK (ROWS/TM)              // 512
#define RESPAD 132                  // res row stride (floats), 16B-aligned
#define OUT_ELEMS (BATCH*DIMS*SEQ)  // 4194304
#define IDX_ELEMS (BATCH*SEQ*NQ)    // 262144
#define LOSS_DIV (1.0f/33554432.0f) // 1/(Q*B*N*D)
#define FRAG_HALVES ((size_t)NQ*4*256*64*8)   // per hi/lo: 4.19M f16 = 8 MB

// ---------------- prep: c_sq[q][k] = sum_d cb^2 ----------------
__global__ void prep_csq(const float* __restrict__ cb, float* __restrict__ csq) {
    int c = blockIdx.x * 256 + threadIdx.x;   // q*4096+k
    const float4* p = (const float4*)(cb + (size_t)c * DIMS);
    float s = 0.f;
#pragma unroll
    for (int i = 0; i < 32; ++i) {
        float4 v = p[i];
        s += v.x * v.x + v.y * v.y + v.z * v.z + v.w * v.w;
    }
    csq[c] = s;
}

// ---------------- prep: codebook -> f16 hi/lo MFMA B-fragments ----------------
// mfma_f32_16x16x32_f16 B-operand: lane l holds B[k=(l>>4)*8+j][n=l&15], j=0..7.
// Storage: frag g = ((q*4+kb)*256+nt)*64+lane at bhi/blo + g*8 halves.
__global__ void prep_frags(const float* __restrict__ cb, _Float16* __restrict__ bhi,
                           _Float16* __restrict__ blo, float* __restrict__ loss_accum) {
    int g = blockIdx.x * 256 + threadIdx.x;   // 524288 total
    if (g == 0) loss_accum[0] = 0.f;
    int lane = g & 63;
    int nt   = (g >> 6) & 255;
    int kb   = (g >> 14) & 3;
    int q    = g >> 16;
    int code = nt * 16 + (lane & 15);
    int k0   = kb * 32 + ((lane >> 4) * 8);
    const float* src = cb + ((size_t)q * KCODES + code) * DIMS + k0;
    float4 v0 = *(const float4*)(src);
    float4 v1 = *(const float4*)(src + 4);
    float f[8] = { v0.x, v0.y, v0.z, v0.w, v1.x, v1.y, v1.z, v1.w };
    half8 h, l;
#pragma unroll
    for (int j = 0; j < 8; ++j) {
        _Float16 hh = (_Float16)f[j];
        h[j] = hh;
        l[j] = (_Float16)(f[j] - (float)hh);
    }
    *(half8*)(bhi + (size_t)g * 8) = h;
    *(half8*)(blo + (size_t)g * 8) = l;
}

// ---------------- main RVQ kernel ----------------
__device__ __forceinline__ void load_b(const _Float16* __restrict__ bq_hi,
                                       const _Float16* __restrict__ bq_lo,
                                       const float* __restrict__ csqq,
                                       int nt, int lane,
                                       half8 (&bh)[4], half8 (&bl)[4], float& cs) {
#pragma unroll
    for (int kb = 0; kb < 4; ++kb) {
        size_t off = (((size_t)kb * 256 + nt) * 64 + lane) * 8;
        bh[kb] = *(const half8*)(bq_hi + off);
        bl[kb] = *(const half8*)(bq_lo + off);
    }
    cs = csqq[nt * 16 + (lane & 15)];
}

__device__ __forceinline__ void compute_tile(int nt, float fcol,
                                             const half8 (&ahi)[4][4], const half8 (&alo)[4][4],
                                             const half8 (&bh)[4], const half8 (&bl)[4], float cs,
                                             float (&bestd)[4][4], float (&besti)[4][4]) {
    float nh = -0.5f * cs;
    float4v acc[4];
#pragma unroll
    for (int mt = 0; mt < 4; ++mt) { acc[mt][0] = nh; acc[mt][1] = nh; acc[mt][2] = nh; acc[mt][3] = nh; }
    // both bh-dependent groups first (defer the bl waitcnt)
#pragma unroll
    for (int kb = 0; kb < 4; ++kb)
#pragma unroll
        for (int mt = 0; mt < 4; ++mt) {
            acc[mt] = __builtin_amdgcn_mfma_f32_16x16x32_f16(ahi[mt][kb], bh[kb], acc[mt], 0, 0, 0);
            acc[mt] = __builtin_amdgcn_mfma_f32_16x16x32_f16(alo[mt][kb], bh[kb], acc[mt], 0, 0, 0);
        }
#pragma unroll
    for (int kb = 0; kb < 4; ++kb)
#pragma unroll
        for (int mt = 0; mt < 4; ++mt)
            acc[mt] = __builtin_amdgcn_mfma_f32_16x16x32_f16(ahi[mt][kb], bl[kb], acc[mt], 0, 0, 0);

    // key = dot - csq/2; argMAX == argmin(csq - 2*dot); strict > keeps first index
    float fidx = (float)(nt * 16) + fcol;
#pragma unroll
    for (int mt = 0; mt < 4; ++mt)
#pragma unroll
        for (int r = 0; r < 4; ++r) {
            float key = acc[mt][r];
            if (key > bestd[mt][r]) { bestd[mt][r] = key; besti[mt][r] = fidx; }
        }
}

__launch_bounds__(256, 2)
__global__ void rvq_main(const float* __restrict__ x, const float* __restrict__ cb,
                         const _Float16* __restrict__ bhi, const _Float16* __restrict__ blo,
                         const float* __restrict__ csq,
                         float* __restrict__ out, float* __restrict__ loss_accum) {
    __shared__ float res[TM][RESPAD];   // residual, row-major fp32
    __shared__ float wbd[4][TM];        // per-wave best key
    __shared__ float wbi[4][TM];        // per-wave best idx (as float)
    __shared__ float fbin[TM];          // final best idx per row
    __shared__ float red[256];

    int tid  = threadIdx.x;
    int lane = tid & 63;
    int wv   = tid >> 6;
    int r0   = blockIdx.x * TM;
    int b    = r0 >> 12;                // / SEQ
    int n0   = r0 & (SEQ - 1);
    const float* xb = x + (size_t)b * DIMS * SEQ + n0;
    float fcol = (float)(lane & 15);

    // load x[b][d][n0..n0+63] into res[n][d]
    {
        int d = tid >> 1, half = (tid & 1) * 32;
        const float* src = xb + (size_t)d * SEQ + half;
#pragma unroll
        for (int t4 = 0; t4 < 8; ++t4) {
            float4 v = *(const float4*)(src + t4 * 4);
            res[half + t4 * 4 + 0][d] = v.x;
            res[half + t4 * 4 + 1][d] = v.y;
            res[half + t4 * 4 + 2][d] = v.z;
            res[half + t4 * 4 + 3][d] = v.w;
        }
    }

    float lossacc = 0.f;

    for (int q = 0; q < NQ; ++q) {
        __syncthreads();   // res stable

        // build A fragments (hi/lo) in registers/AGPRs
        half8 ahi[4][4], alo[4][4];
#pragma unroll
        for (int mt = 0; mt < 4; ++mt)
#pragma unroll
        for (int kb = 0; kb < 4; ++kb) {
            int row = mt * 16 + (lane & 15);
            int k0  = kb * 32 + (lane >> 4) * 8;
            float4 v0 = *(const float4*)&res[row][k0];
            float4 v1 = *(const float4*)&res[row][k0 + 4];
            float f[8] = { v0.x, v0.y, v0.z, v0.w, v1.x, v1.y, v1.z, v1.w };
            half8 h, l;
#pragma unroll
            for (int j = 0; j < 8; ++j) {
                _Float16 hh = (_Float16)f[j];
                h[j] = hh;
                l[j] = (_Float16)(f[j] - (float)hh);
            }
            ahi[mt][kb] = h;
            alo[mt][kb] = l;
        }

        const _Float16* bq_hi = bhi + (size_t)q * (4 * 256 * 64 * 8);
        const _Float16* bq_lo = blo + (size_t)q * (4 * 256 * 64 * 8);
        const float*    csqq  = csq + q * KCODES;

        float bestd[4][4], besti[4][4];
#pragma unroll
        for (int mt = 0; mt < 4; ++mt)
#pragma unroll
        for (int r = 0; r < 4; ++r) { bestd[mt][r] = -3.4e38f; besti[mt][r] = 0.f; }

        // each wave owns n-tiles [wv*64, wv*64+64); double-buffered B prefetch
        int ntBase = wv * 64;
        half8 bh0[4], bl0[4], bh1[4], bl1[4];
        float cs0, cs1;
        load_b(bq_hi, bq_lo, csqq, ntBase, lane, bh0, bl0, cs0);
        for (int i = 0; i < 64; i += 2) {
            load_b(bq_hi, bq_lo, csqq, ntBase + i + 1, lane, bh1, bl1, cs1);
            compute_tile(ntBase + i, fcol, ahi, alo, bh0, bl0, cs0, bestd, besti);
            load_b(bq_hi, bq_lo, csqq, ntBase + ((i + 2) & 63), lane, bh0, bl0, cs0);
            compute_tile(ntBase + i + 1, fcol, ahi, alo, bh1, bl1, cs1, bestd, besti);
        }

        // reduce across the 16 lanes sharing each row (low 4 lane bits)
#pragma unroll
        for (int mask = 1; mask <= 8; mask <<= 1) {
#pragma unroll
            for (int mt = 0; mt < 4; ++mt)
#pragma unroll
            for (int r = 0; r < 4; ++r) {
                float od = __shfl_xor(bestd[mt][r], mask, 64);
                float oi = __shfl_xor(besti[mt][r], mask, 64);
                if (od > bestd[mt][r] || (od == bestd[mt][r] && oi < besti[mt][r])) {
                    bestd[mt][r] = od;
                    besti[mt][r] = oi;
                }
            }
        }
        if ((lane & 15) == 0) {
            int qd = lane >> 4;
#pragma unroll
            for (int mt = 0; mt < 4; ++mt)
#pragma unroll
            for (int r = 0; r < 4; ++r) {
                int row = mt * 16 + qd * 4 + r;
                wbd[wv][row] = bestd[mt][r];
                wbi[wv][row] = besti[mt][r];
            }
        }
        __syncthreads();

        // cross-wave reduce (waves cover ascending code ranges; tie -> smaller idx)
        if (tid < TM) {
            float bd = wbd[0][tid], bi = wbi[0][tid];
#pragma unroll
            for (int w = 1; w < 4; ++w) {
                float dd = wbd[w][tid], ii = wbi[w][tid];
                if (dd > bd || (dd == bd && ii < bi)) { bd = dd; bi = ii; }
            }
            fbin[tid] = bi;
            out[OUT_ELEMS + (size_t)(r0 + tid) * NQ + q] = bi;   // index output (float)
        }
        __syncthreads();

        // residual update + commitment-loss accumulation (bank-conflict-free mapping)
        {
            int row = tid >> 2, j = tid & 3;
            int bi = (int)fbin[row];
            const float* cv = cb + ((size_t)q * KCODES + bi) * DIMS + j * 4;
            float* rp = &res[row][j * 4];
#pragma unroll
            for (int t = 0; t < 8; ++t) {
                float4 c4 = *(const float4*)(cv + t * 16);
                float4 r4 = *(const float4*)(rp + t * 16);
                r4.x -= c4.x; lossacc = fmaf(r4.x, r4.x, lossacc);
                r4.y -= c4.y; lossacc = fmaf(r4.y, r4.y, lossacc);
                r4.z -= c4.z; lossacc = fmaf(r4.z, r4.z, lossacc);
                r4.w -= c4.w; lossacc = fmaf(r4.w, r4.w, lossacc);
                *(float4*)(rp + t * 16) = r4;
            }
        }
    }

    // loss reduction
    __syncthreads();
    red[tid] = lossacc;
    __syncthreads();
    for (int s = 128; s > 0; s >>= 1) {
        if (tid < s) red[tid] += red[tid + s];
        __syncthreads();
    }
    if (tid == 0) atomicAdd(loss_accum, red[0]);

    // quantized output: out = x - final_residual
    {
        int d = tid >> 1, half = (tid & 1) * 32;
        const float* src = xb + (size_t)d * SEQ + half;
        float* dst = out + (size_t)b * DIMS * SEQ + (size_t)d * SEQ + n0 + half;
#pragma unroll
        for (int t4 = 0; t4 < 8; ++t4) {
            float4 v = *(const float4*)(src + t4 * 4);
            v.x -= res[half + t4 * 4 + 0][d];
            v.y -= res[half + t4 * 4 + 1][d];
            v.z -= res[half + t4 * 4 + 2][d];
            v.w -= res[half + t4 * 4 + 3][d];
            *(float4*)(dst + t4 * 4) = v;
        }
    }
}

__global__ void finish_loss(const float* __restrict__ loss_accum, float* __restrict__ out) {
    out[OUT_ELEMS + IDX_ELEMS] = loss_accum[0] * LOSS_DIV;
}

extern "C" void kernel_launch(void* const* d_in, const int* in_sizes, int n_in,
                              void* d_out, int out_size, void* d_ws, size_t ws_size,
                              hipStream_t stream) {
    const float* x  = (const float*)d_in[0];
    const float* cb = (const float*)d_in[1];
    float* out = (float*)d_out;
    char*  ws  = (char*)d_ws;

    float*     loss_accum = (float*)ws;
    float*     csq = (float*)(ws + 256);
    _Float16*  bhi = (_Float16*)(ws + 256 + 131072);
    _Float16*  blo = (_Float16*)(ws + 256 + 131072 + FRAG_HALVES * 2);

    hipLaunchKernelGGL(prep_csq,   dim3(128),  dim3(256), 0, stream, cb, csq);
    hipLaunchKernelGGL(prep_frags, dim3(2048), dim3(256), 0, stream, cb, bhi, blo, loss_accum);
    hipLaunchKernelGGL(rvq_main,   dim3(NBLK), dim3(256), 0, stream,
                       x, cb, bhi, blo, csq, out, loss_accum);
    hipLaunchKernelGGL(finish_loss, dim3(1), dim3(1), 0, stream, loss_accum, out);
}